// Round 9
// baseline (72.640 us; speedup 1.0000x reference)
//
#include <hip/hip_runtime.h>

// KiloNeRF fused MLP — all-MFMA, 4-wave-occupancy version.
// Per 16-point tile each layer is C = W^T(16xK) @ act(Kx16) via
// mfma_f32_16x16x32_f16; positional k-map sigma(g,j) on BOTH A and B keeps
// activations lane-local. R9 register cuts (target: <=128 total regs incl
// AGPR -> 4 waves/SIMD):
//  - ONE input fragment bx per tile: pts+1.0 in k-slots 0..3, views+1.0 in
//    k-slots 16..19. L0's A is zero at k>=4; views-partial A is zero at
//    k<16 -> both MFMAs consume the same bx (garbage-slot trick).
//  - L1/feature biases f16-packed, added via v_pk_add_f16 post-pkrtz;
//    all MFMA C-inits are a shared zero quad.
//  - rgb/sigma biases added at store from uniform scalars (SGPRs).

#define NPTS   4194304
#define NTILES (NPTS / 16)

typedef _Float16 f16;
typedef _Float16 f16x2 __attribute__((ext_vector_type(2)));
typedef _Float16 f16x8 __attribute__((ext_vector_type(8)));
typedef float    f32x4 __attribute__((ext_vector_type(4)));

union H8 { f16x8 v; unsigned u[4]; };

static __device__ __forceinline__ unsigned pkrtz(float a, float b) {
    return __builtin_bit_cast(unsigned, __builtin_amdgcn_cvt_pkrtz(a, b));
}
static __device__ __forceinline__ unsigned relu2(unsigned w) {
    f16x2 h = __builtin_bit_cast(f16x2, w);
    f16x2 z = (f16x2)(f16)0.f;
    return __builtin_bit_cast(unsigned, __builtin_elementwise_max(h, z));
}
static __device__ __forceinline__ unsigned addpk(unsigned a, unsigned b) {
    f16x2 x = __builtin_bit_cast(f16x2, a);
    f16x2 y = __builtin_bit_cast(f16x2, b);
    f16x2 s = x + y;   // v_pk_add_f16
    return __builtin_bit_cast(unsigned, s);
}

#define MFMA(A, B, C) __builtin_amdgcn_mfma_f32_16x16x32_f16((A), (B), (C), 0, 0, 0)

__global__ __launch_bounds__(256, 4) void kilonerf_r9(
    const float* __restrict__ x,
    const float* __restrict__ w0, const float* __restrict__ b0,
    const float* __restrict__ w1, const float* __restrict__ b1,
    const float* __restrict__ wf, const float* __restrict__ bf,
    const float* __restrict__ ws, const float* __restrict__ bs,
    const float* __restrict__ wv, const float* __restrict__ bv,
    const float* __restrict__ wr, const float* __restrict__ br,
    float* __restrict__ out)
{
    const int lane = threadIdx.x & 63;
    const int g = lane >> 4;      // lane group 0..3
    const int c = lane & 15;      // column (point within tile) / row-of-A

    // positional k-map (same for A and B)
    int kk[8];
#pragma unroll
    for (int j = 0; j < 8; ++j) kk[j] = (j < 4) ? (4 * g + j) : (16 + 4 * g + (j - 4));

    // ---- one-time per-wave weight fragment gathers (RTN) ----
    // aw0: w0 rows at k=0..2, b0 at k=3, zero at k>=4.
    // awv2: wv "views" rows at k=16..18, bv at k=19, zero elsewhere.
    f16x8 aw0[2], aw1[2], awf[2], awv[2], awv2[2], aws, awr;
#pragma unroll
    for (int t = 0; t < 2; ++t) {
#pragma unroll
        for (int j = 0; j < 8; ++j) {
            const int m = c + 16 * t;
            const int k = kk[j];
            aw0[t][j]  = (k < 3) ? (f16)w0[k * 32 + m]
                        : (k == 3 ? (f16)b0[m] : (f16)0.f);
            aw1[t][j]  = (f16)w1[k * 32 + m];
            awf[t][j]  = (f16)wf[k * 32 + m];
            awv[t][j]  = (f16)wv[k * 32 + m];
            awv2[t][j] = (k >= 16 && k < 19) ? (f16)wv[(32 + (k - 16)) * 32 + m]
                        : (k == 19 ? (f16)bv[m] : (f16)0.f);
        }
    }
#pragma unroll
    for (int j = 0; j < 8; ++j) {
        aws[j] = (c == 0) ? (f16)ws[kk[j]] : (f16)0.f;
        awr[j] = (c < 3) ? (f16)wr[kk[j] * 3 + c] : (f16)0.f;
    }

    // f16-packed biases for L1 / feature, aligned to bh-word layout:
    // word 0: rows (4g+0,4g+1), word 1: (4g+2,4g+3), words 2,3: +16.
    unsigned b1pk[4], bfpk[4];
#pragma unroll
    for (int t = 0; t < 2; ++t) {
        const int m = 4 * g + 16 * t;
        b1pk[2 * t + 0] = pkrtz(b1[m + 0], b1[m + 1]);
        b1pk[2 * t + 1] = pkrtz(b1[m + 2], b1[m + 3]);
        bfpk[2 * t + 0] = pkrtz(bf[m + 0], bf[m + 1]);
        bfpk[2 * t + 1] = pkrtz(bf[m + 2], bf[m + 3]);
    }

    // rgb/sigma biases: uniform scalars (SGPR-resident)
    const float br0 = br[0], br1 = br[1], br2 = br[2], bs0 = bs[0];

    const f32x4 zf = {0.f, 0.f, 0.f, 0.f};

    const int wslot  = blockIdx.x * 4 + (threadIdx.x >> 6);
    const int nslots = gridDim.x * 4;   // 8192 waves
    const int npairs = NTILES / 2;      // 131072

    for (int pair = wslot; pair < npairs; pair += nslots) {
        // ---- load x, build the merged input fragment per tile ----
        H8 bx[2];
#pragma unroll
        for (int u = 0; u < 2; ++u) {
            const float2* xp2 = reinterpret_cast<const float2*>(
                x + (size_t)(pair * 32 + u * 16 + c) * 6);
            const float2 a0 = xp2[0], a1 = xp2[1], a2 = xp2[2];
            bx[u].u[0] = pkrtz(a0.x, a0.y);    // p0, p1   (k=0,1)
            bx[u].u[1] = pkrtz(a1.x, 1.0f);    // p2, 1.0  (k=2,3)
            bx[u].u[2] = pkrtz(a1.y, a2.x);    // v0, v1   (k=16,17)
            bx[u].u[3] = pkrtz(a2.y, 1.0f);    // v2, 1.0  (k=18,19)
        }

        // ---- layer 0: 3 -> 32 (+b0 via k=3), relu ----
        f32x4 c00[2], c01[2];
#pragma unroll
        for (int u = 0; u < 2; ++u) {
            c00[u] = MFMA(aw0[0], bx[u].v, zf);
            c01[u] = MFMA(aw0[1], bx[u].v, zf);
        }
        // ---- view partial: views(3)+bv via k=16..19 (independent chain) ----
        f32x4 cv0[2], cv1[2];
#pragma unroll
        for (int u = 0; u < 2; ++u) {
            cv0[u] = MFMA(awv2[0], bx[u].v, zf);
            cv1[u] = MFMA(awv2[1], bx[u].v, zf);
        }

        H8 bh0[2];
#pragma unroll
        for (int u = 0; u < 2; ++u) {
            bh0[u].u[0] = relu2(pkrtz(c00[u][0], c00[u][1]));
            bh0[u].u[1] = relu2(pkrtz(c00[u][2], c00[u][3]));
            bh0[u].u[2] = relu2(pkrtz(c01[u][0], c01[u][1]));
            bh0[u].u[3] = relu2(pkrtz(c01[u][2], c01[u][3]));
        }

        // ---- layer 1: 32 -> 32, +b1 (pk), relu ----
        f32x4 c10[2], c11[2];
#pragma unroll
        for (int u = 0; u < 2; ++u) {
            c10[u] = MFMA(aw1[0], bh0[u].v, zf);
            c11[u] = MFMA(aw1[1], bh0[u].v, zf);
        }
        H8 bh1[2];
#pragma unroll
        for (int u = 0; u < 2; ++u) {
            bh1[u].u[0] = relu2(addpk(pkrtz(c10[u][0], c10[u][1]), b1pk[0]));
            bh1[u].u[1] = relu2(addpk(pkrtz(c10[u][2], c10[u][3]), b1pk[1]));
            bh1[u].u[2] = relu2(addpk(pkrtz(c11[u][0], c11[u][1]), b1pk[2]));
            bh1[u].u[3] = relu2(addpk(pkrtz(c11[u][2], c11[u][3]), b1pk[3]));
        }

        // ---- sigma: 32 -> 1 (row 0 of A valid; +bs at store) ----
        f32x4 cs[2];
#pragma unroll
        for (int u = 0; u < 2; ++u) cs[u] = MFMA(aws, bh1[u].v, zf);

        // ---- feature: 32 -> 32, +bf (pk), no relu ----
        f32x4 cf0[2], cf1[2];
#pragma unroll
        for (int u = 0; u < 2; ++u) {
            cf0[u] = MFMA(awf[0], bh1[u].v, zf);
            cf1[u] = MFMA(awf[1], bh1[u].v, zf);
        }
        H8 bft[2];
#pragma unroll
        for (int u = 0; u < 2; ++u) {
            bft[u].u[0] = addpk(pkrtz(cf0[u][0], cf0[u][1]), bfpk[0]);
            bft[u].u[1] = addpk(pkrtz(cf0[u][2], cf0[u][3]), bfpk[1]);
            bft[u].u[2] = addpk(pkrtz(cf1[u][0], cf1[u][1]), bfpk[2]);
            bft[u].u[3] = addpk(pkrtz(cf1[u][2], cf1[u][3]), bfpk[3]);
        }

        // ---- view layer: accumulate feat into views partial, relu ----
#pragma unroll
        for (int u = 0; u < 2; ++u) {
            cv0[u] = MFMA(awv[0], bft[u].v, cv0[u]);
            cv1[u] = MFMA(awv[1], bft[u].v, cv1[u]);
        }
        H8 bhv[2];
#pragma unroll
        for (int u = 0; u < 2; ++u) {
            bhv[u].u[0] = relu2(pkrtz(cv0[u][0], cv0[u][1]));
            bhv[u].u[1] = relu2(pkrtz(cv0[u][2], cv0[u][3]));
            bhv[u].u[2] = relu2(pkrtz(cv1[u][0], cv1[u][1]));
            bhv[u].u[3] = relu2(pkrtz(cv1[u][2], cv1[u][3]));
        }

        // ---- rgb: 32 -> 3 (rows 0..2 of A valid; +br at store) ----
        f32x4 cr[2];
#pragma unroll
        for (int u = 0; u < 2; ++u) cr[u] = MFMA(awr, bhv[u].v, zf);

        // ---- store: lanes 0..15 hold rgb (regs 0..2) + sigma (reg 0) ----
        if (g == 0) {
#pragma unroll
            for (int u = 0; u < 2; ++u) {
                float4 o = make_float4(cr[u][0] + br0, cr[u][1] + br1,
                                       cr[u][2] + br2, cs[u][0] + bs0);
                *reinterpret_cast<float4*>(out + (size_t)(pair * 32 + u * 16 + c) * 4) = o;
            }
        }
    }
}

extern "C" void kernel_launch(void* const* d_in, const int* in_sizes, int n_in,
                              void* d_out, int out_size, void* d_ws, size_t ws_size,
                              hipStream_t stream) {
    const float* x  = (const float*)d_in[0];
    const float* w0 = (const float*)d_in[1];
    const float* b0 = (const float*)d_in[2];
    const float* w1 = (const float*)d_in[3];
    const float* b1 = (const float*)d_in[4];
    const float* wf = (const float*)d_in[5];
    const float* bf = (const float*)d_in[6];
    const float* ws = (const float*)d_in[7];
    const float* bs = (const float*)d_in[8];
    const float* wv = (const float*)d_in[9];
    const float* bv = (const float*)d_in[10];
    const float* wr = (const float*)d_in[11];
    const float* br = (const float*)d_in[12];
    float* out = (float*)d_out;

    dim3 block(256);
    dim3 grid(2048);
    kilonerf_r9<<<grid, block, 0, stream>>>(x, w0, b0, w1, b1, wf, bf,
                                            ws, bs, wv, bv, wr, br, out);
}

// Round 10
// 63.033 us; speedup vs baseline: 1.1524x; 1.1524x over previous
//
#include <hip/hip_runtime.h>

// KiloNeRF fused MLP — all-MFMA, single-tile / high-TLP version.
// Per 16-point tile each layer is C = W^T(16xK) @ act(Kx16) via
// mfma_f32_16x16x32_f16; positional k-map sigma(g,j) on BOTH A and B keeps
// activations lane-local. R10: ONE tile per wave (halves accumulator AGPRs
// vs R8's 2-tile ILP) + __launch_bounds__(256,5) -> target 5 waves/SIMD;
// TLP replaces ILP for latency hiding.
//  - merged input fragment bx: pts+1.0 in k=0..3, views+1.0 in k=16..19;
//    L0's A is zero at k>=4, view-partial A zero outside k=16..19.
//  - b0/bv folded into A rows (k=3 / k=19); b1/bf ride the MFMA C-init
//    (R8 scheme — R9's post-MFMA addpk chain was the regression);
//    br/bs added at store from uniform scalars.

#define NPTS   4194304
#define NTILES (NPTS / 16)

typedef _Float16 f16;
typedef _Float16 f16x2 __attribute__((ext_vector_type(2)));
typedef _Float16 f16x8 __attribute__((ext_vector_type(8)));
typedef float    f32x4 __attribute__((ext_vector_type(4)));

union H8 { f16x8 v; unsigned u[4]; };

static __device__ __forceinline__ unsigned pkrtz(float a, float b) {
    return __builtin_bit_cast(unsigned, __builtin_amdgcn_cvt_pkrtz(a, b));
}
static __device__ __forceinline__ unsigned relu2(unsigned w) {
    f16x2 h = __builtin_bit_cast(f16x2, w);
    f16x2 z = (f16x2)(f16)0.f;
    return __builtin_bit_cast(unsigned, __builtin_elementwise_max(h, z));
}

#define MFMA(A, B, C) __builtin_amdgcn_mfma_f32_16x16x32_f16((A), (B), (C), 0, 0, 0)

__global__ __launch_bounds__(256, 5) void kilonerf_r10(
    const float* __restrict__ x,
    const float* __restrict__ w0, const float* __restrict__ b0,
    const float* __restrict__ w1, const float* __restrict__ b1,
    const float* __restrict__ wf, const float* __restrict__ bf,
    const float* __restrict__ ws, const float* __restrict__ bs,
    const float* __restrict__ wv, const float* __restrict__ bv,
    const float* __restrict__ wr, const float* __restrict__ br,
    float* __restrict__ out)
{
    const int lane = threadIdx.x & 63;
    const int g = lane >> 4;      // lane group 0..3
    const int c = lane & 15;      // column (point within tile) / row-of-A

    // positional k-map (same for A and B)
    int kk[8];
#pragma unroll
    for (int j = 0; j < 8; ++j) kk[j] = (j < 4) ? (4 * g + j) : (16 + 4 * g + (j - 4));

    // ---- one-time per-wave weight fragment gathers (RTN) ----
    // aw0: w0 rows at k=0..2, b0 at k=3, zero at k>=4.
    // awv2: wv "views" rows at k=16..18, bv at k=19, zero elsewhere.
    f16x8 aw0[2], aw1[2], awf[2], awv[2], awv2[2], aws, awr;
#pragma unroll
    for (int t = 0; t < 2; ++t) {
#pragma unroll
        for (int j = 0; j < 8; ++j) {
            const int m = c + 16 * t;
            const int k = kk[j];
            aw0[t][j]  = (k < 3) ? (f16)w0[k * 32 + m]
                        : (k == 3 ? (f16)b0[m] : (f16)0.f);
            aw1[t][j]  = (f16)w1[k * 32 + m];
            awf[t][j]  = (f16)wf[k * 32 + m];
            awv[t][j]  = (f16)wv[k * 32 + m];
            awv2[t][j] = (k >= 16 && k < 19) ? (f16)wv[(32 + (k - 16)) * 32 + m]
                        : (k == 19 ? (f16)bv[m] : (f16)0.f);
        }
    }
#pragma unroll
    for (int j = 0; j < 8; ++j) {
        aws[j] = (c == 0) ? (f16)ws[kk[j]] : (f16)0.f;
        awr[j] = (c < 3) ? (f16)wr[kk[j] * 3 + c] : (f16)0.f;
    }

    // bias C-inits for L1 / feature (reg r = row 4g+r (+16t))
    f32x4 b1f[2], bff[2];
#pragma unroll
    for (int t = 0; t < 2; ++t)
#pragma unroll
        for (int r = 0; r < 4; ++r) {
            const int m = 4 * g + r + 16 * t;
            b1f[t][r] = b1[m];
            bff[t][r] = bf[m];
        }

    // rgb/sigma biases: uniform scalars (SGPR-resident)
    const float br0 = br[0], br1 = br[1], br2 = br[2], bs0 = bs[0];

    const f32x4 zf = {0.f, 0.f, 0.f, 0.f};

    const int wslot  = blockIdx.x * 4 + (threadIdx.x >> 6);
    const int nslots = gridDim.x * 4;   // 8192 waves

    for (int tile = wslot; tile < NTILES; tile += nslots) {
        // ---- load x, build the merged input fragment ----
        const float2* xp2 = reinterpret_cast<const float2*>(
            x + (size_t)(tile * 16 + c) * 6);
        const float2 a0 = xp2[0], a1 = xp2[1], a2 = xp2[2];
        H8 bx;
        bx.u[0] = pkrtz(a0.x, a0.y);    // p0, p1   (k=0,1)
        bx.u[1] = pkrtz(a1.x, 1.0f);    // p2, 1.0  (k=2,3)
        bx.u[2] = pkrtz(a1.y, a2.x);    // v0, v1   (k=16,17)
        bx.u[3] = pkrtz(a2.y, 1.0f);    // v2, 1.0  (k=18,19)

        // ---- layer 0: 3 -> 32 (+b0 via k=3), relu ----
        f32x4 c00 = MFMA(aw0[0], bx.v, zf);
        f32x4 c01 = MFMA(aw0[1], bx.v, zf);
        // ---- view partial: views(3)+bv via k=16..19 (independent chain) ----
        f32x4 cv0 = MFMA(awv2[0], bx.v, zf);
        f32x4 cv1 = MFMA(awv2[1], bx.v, zf);

        H8 bh0;
        bh0.u[0] = relu2(pkrtz(c00[0], c00[1]));
        bh0.u[1] = relu2(pkrtz(c00[2], c00[3]));
        bh0.u[2] = relu2(pkrtz(c01[0], c01[1]));
        bh0.u[3] = relu2(pkrtz(c01[2], c01[3]));

        // ---- layer 1: 32 -> 32 (+b1 via C-init), relu ----
        f32x4 c10 = MFMA(aw1[0], bh0.v, b1f[0]);
        f32x4 c11 = MFMA(aw1[1], bh0.v, b1f[1]);
        H8 bh1;
        bh1.u[0] = relu2(pkrtz(c10[0], c10[1]));
        bh1.u[1] = relu2(pkrtz(c10[2], c10[3]));
        bh1.u[2] = relu2(pkrtz(c11[0], c11[1]));
        bh1.u[3] = relu2(pkrtz(c11[2], c11[3]));

        // ---- sigma: 32 -> 1 (row 0 of A valid; +bs at store) ----
        f32x4 cs = MFMA(aws, bh1.v, zf);

        // ---- feature: 32 -> 32 (+bf via C-init), no relu ----
        f32x4 cf0 = MFMA(awf[0], bh1.v, bff[0]);
        f32x4 cf1 = MFMA(awf[1], bh1.v, bff[1]);
        H8 bft;
        bft.u[0] = pkrtz(cf0[0], cf0[1]);
        bft.u[1] = pkrtz(cf0[2], cf0[3]);
        bft.u[2] = pkrtz(cf1[0], cf1[1]);
        bft.u[3] = pkrtz(cf1[2], cf1[3]);

        // ---- view layer: accumulate feat into views partial, relu ----
        cv0 = MFMA(awv[0], bft.v, cv0);
        cv1 = MFMA(awv[1], bft.v, cv1);
        H8 bhv;
        bhv.u[0] = relu2(pkrtz(cv0[0], cv0[1]));
        bhv.u[1] = relu2(pkrtz(cv0[2], cv0[3]));
        bhv.u[2] = relu2(pkrtz(cv1[0], cv1[1]));
        bhv.u[3] = relu2(pkrtz(cv1[2], cv1[3]));

        // ---- rgb: 32 -> 3 (rows 0..2 of A valid; +br at store) ----
        f32x4 cr = MFMA(awr, bhv.v, zf);

        // ---- store: lanes 0..15 hold rgb (regs 0..2) + sigma (reg 0) ----
        if (g == 0) {
            float4 o = make_float4(cr[0] + br0, cr[1] + br1,
                                   cr[2] + br2, cs[0] + bs0);
            *reinterpret_cast<float4*>(out + (size_t)(tile * 16 + c) * 4) = o;
        }
    }
}

extern "C" void kernel_launch(void* const* d_in, const int* in_sizes, int n_in,
                              void* d_out, int out_size, void* d_ws, size_t ws_size,
                              hipStream_t stream) {
    const float* x  = (const float*)d_in[0];
    const float* w0 = (const float*)d_in[1];
    const float* b0 = (const float*)d_in[2];
    const float* w1 = (const float*)d_in[3];
    const float* b1 = (const float*)d_in[4];
    const float* wf = (const float*)d_in[5];
    const float* bf = (const float*)d_in[6];
    const float* ws = (const float*)d_in[7];
    const float* bs = (const float*)d_in[8];
    const float* wv = (const float*)d_in[9];
    const float* bv = (const float*)d_in[10];
    const float* wr = (const float*)d_in[11];
    const float* br = (const float*)d_in[12];
    float* out = (float*)d_out;

    dim3 block(256);
    dim3 grid(2048);
    kilonerf_r10<<<grid, block, 0, stream>>>(x, w0, b0, w1, b1, wf, bf,
                                             ws, bs, wv, bv, wr, br, out);
}

// Round 11
// 62.658 us; speedup vs baseline: 1.1593x; 1.0060x over previous
//
#include <hip/hip_runtime.h>

// KiloNeRF fused MLP — 32x32x16 MFMA version.
// Per 32-point tile each layer is C = W^T(32xK) @ act(Kx32) via
// mfma_f32_32x32x16_f16 (cols = points). Positional k-map
// sigma(hi,j) = (j&3)+8*(j>>2)+4*hi applied to BOTH A and B keeps
// activations lane-local: C layout row=(reg&3)+8*(reg>>2)+4*hi, col=lane&31
// means next-layer B fragments are B1[j]=f16(C[j]), B2[j]=f16(C[j+8]).
//  - L0 (pts) and view-partial (views) share ONE input fragment bx:
//    pts+1.0 at k=0..3, views+1.0 at k=4..7 (A-side garbage-slot zeros).
//  - b0, bvEff folded into A rows; bvEff = bv + Wv_feat·bf (f32 setup)
//    also absorbs the feature bias. b1 rides the L1 C-init.
//  - sigma on the f32 VALU pipe (16 FMA + shfl_xor(32)), off the MFMA pipe.
//  - br/bs added at store.

#define NPTS   4194304
#define NT32   (NPTS / 32)

typedef _Float16 f16;
typedef _Float16 f16x2 __attribute__((ext_vector_type(2)));
typedef _Float16 f16x8 __attribute__((ext_vector_type(8)));
typedef float    f32x16 __attribute__((ext_vector_type(16)));

union H8 { f16x8 v; unsigned u[4]; };

static __device__ __forceinline__ unsigned pkrtz(float a, float b) {
    return __builtin_bit_cast(unsigned, __builtin_amdgcn_cvt_pkrtz(a, b));
}
static __device__ __forceinline__ unsigned relu2(unsigned w) {
    f16x2 h = __builtin_bit_cast(f16x2, w);
    f16x2 z = (f16x2)(f16)0.f;
    return __builtin_bit_cast(unsigned, __builtin_elementwise_max(h, z));
}

#define MFMA32(A, B, C) __builtin_amdgcn_mfma_f32_32x32x16_f16((A), (B), (C), 0, 0, 0)

__global__ __launch_bounds__(256, 4) void kilonerf_m32(
    const float* __restrict__ x,
    const float* __restrict__ w0, const float* __restrict__ b0,
    const float* __restrict__ w1, const float* __restrict__ b1,
    const float* __restrict__ wf, const float* __restrict__ bf,
    const float* __restrict__ ws, const float* __restrict__ bs,
    const float* __restrict__ wv, const float* __restrict__ bv,
    const float* __restrict__ wr, const float* __restrict__ br,
    float* __restrict__ out)
{
    const int lane = threadIdx.x & 63;
    const int m  = lane & 31;     // output channel (A row) / point (B,C col)
    const int hi = lane >> 5;     // lane half

    // positional k-map for A/B slot j (k in [0,16)), and C row per reg
    int sj[8], row[16];
#pragma unroll
    for (int j = 0; j < 8; ++j)  sj[j]  = (j & 3) + 8 * (j >> 2) + 4 * hi;
#pragma unroll
    for (int r = 0; r < 16; ++r) row[r] = (r & 3) + 8 * (r >> 2) + 4 * hi;

    // ---- effective view-layer bias: bv + Wv_feat . bf (absorbs feat bias) ----
    float bve = bv[m];
#pragma unroll 8
    for (int k = 0; k < 32; ++k) bve = fmaf(wv[k * 32 + m], bf[k], bve);

    // ---- one-time weight fragment gathers (RTN) ----
    f16x8 aw0x, awv2x, aw1lo, aw1hi, awflo, awfhi, awvlo, awvhi, awrlo, awrhi;
#pragma unroll
    for (int j = 0; j < 8; ++j) {
        const int k = sj[j];
        aw0x[j]  = (k < 3) ? (f16)w0[k * 32 + m]
                  : (k == 3 ? (f16)b0[m] : (f16)0.f);
        awv2x[j] = (k >= 4 && k < 7) ? (f16)wv[(32 + (k - 4)) * 32 + m]
                  : (k == 7 ? (f16)bve : (f16)0.f);
        aw1lo[j] = (f16)w1[k * 32 + m];
        aw1hi[j] = (f16)w1[(16 + k) * 32 + m];
        awflo[j] = (f16)wf[k * 32 + m];
        awfhi[j] = (f16)wf[(16 + k) * 32 + m];
        awvlo[j] = (f16)wv[k * 32 + m];
        awvhi[j] = (f16)wv[(16 + k) * 32 + m];
        awrlo[j] = (m < 3) ? (f16)wr[k * 3 + m] : (f16)0.f;
        awrhi[j] = (m < 3) ? (f16)wr[(16 + k) * 3 + m] : (f16)0.f;
    }

    // sigma weights (f32, this lane's 16 C-rows) and L1 bias C-init
    float wsv[16];
    f32x16 b1c;
#pragma unroll
    for (int r = 0; r < 16; ++r) {
        wsv[r] = ws[row[r]];
        b1c[r] = b1[row[r]];
    }

    const float br0 = br[0], br1 = br[1], br2 = br[2], bs0 = bs[0];

    f32x16 zf;
#pragma unroll
    for (int r = 0; r < 16; ++r) zf[r] = 0.f;

    const int wslot  = blockIdx.x * 4 + (threadIdx.x >> 6);
    const int nslots = gridDim.x * 4;   // 8192 waves

    for (int tile = wslot; tile < NT32; tile += nslots) {
        // ---- load this lane's point (both halves load the same 32 pts) ----
        const float2* xp2 = reinterpret_cast<const float2*>(
            x + (size_t)(tile * 32 + m) * 6);
        const float2 a0 = xp2[0], a1 = xp2[1], a2 = xp2[2];

        // merged input fragment: hi=0 -> {p0,p1,p2,1}, hi=1 -> {v0,v1,v2,1}
        const float fa = hi ? a1.y : a0.x;
        const float fb = hi ? a2.x : a0.y;
        const float fc = hi ? a2.y : a1.x;
        H8 bx;
        bx.u[0] = pkrtz(fa, fb);
        bx.u[1] = pkrtz(fc, 1.0f);
        bx.u[2] = 0u;
        bx.u[3] = 0u;

        // ---- layer 0: 3 -> 32 (+b0), relu ----
        f32x16 c0 = MFMA32(aw0x, bx.v, zf);
        // ---- view partial: views(3) + bvEff (independent chain) ----
        f32x16 cv = MFMA32(awv2x, bx.v, zf);

        H8 blo, bhi;
        blo.u[0] = relu2(pkrtz(c0[0], c0[1]));
        blo.u[1] = relu2(pkrtz(c0[2], c0[3]));
        blo.u[2] = relu2(pkrtz(c0[4], c0[5]));
        blo.u[3] = relu2(pkrtz(c0[6], c0[7]));
        bhi.u[0] = relu2(pkrtz(c0[8], c0[9]));
        bhi.u[1] = relu2(pkrtz(c0[10], c0[11]));
        bhi.u[2] = relu2(pkrtz(c0[12], c0[13]));
        bhi.u[3] = relu2(pkrtz(c0[14], c0[15]));

        // ---- layer 1: 32 -> 32 (+b1 via C-init), relu ----
        f32x16 c1 = MFMA32(aw1lo, blo.v, b1c);
        c1 = MFMA32(aw1hi, bhi.v, c1);

        // sigma on the VALU pipe: ws . relu(h1), f32
        float s0 = 0.f, s1 = 0.f, s2 = 0.f, s3 = 0.f;
#pragma unroll
        for (int r = 0; r < 4; ++r) {
            s0 = fmaf(fmaxf(c1[r],      0.f), wsv[r],      s0);
            s1 = fmaf(fmaxf(c1[4 + r],  0.f), wsv[4 + r],  s1);
            s2 = fmaf(fmaxf(c1[8 + r],  0.f), wsv[8 + r],  s2);
            s3 = fmaf(fmaxf(c1[12 + r], 0.f), wsv[12 + r], s3);
        }
        float sg = (s0 + s1) + (s2 + s3);
        sg += __shfl_xor(sg, 32);

        blo.u[0] = relu2(pkrtz(c1[0], c1[1]));
        blo.u[1] = relu2(pkrtz(c1[2], c1[3]));
        blo.u[2] = relu2(pkrtz(c1[4], c1[5]));
        blo.u[3] = relu2(pkrtz(c1[6], c1[7]));
        bhi.u[0] = relu2(pkrtz(c1[8], c1[9]));
        bhi.u[1] = relu2(pkrtz(c1[10], c1[11]));
        bhi.u[2] = relu2(pkrtz(c1[12], c1[13]));
        bhi.u[3] = relu2(pkrtz(c1[14], c1[15]));

        // ---- feature: 32 -> 32 (bias absorbed in bvEff), no relu ----
        f32x16 cf = MFMA32(awflo, blo.v, zf);
        cf = MFMA32(awfhi, bhi.v, cf);

        blo.u[0] = pkrtz(cf[0], cf[1]);
        blo.u[1] = pkrtz(cf[2], cf[3]);
        blo.u[2] = pkrtz(cf[4], cf[5]);
        blo.u[3] = pkrtz(cf[6], cf[7]);
        bhi.u[0] = pkrtz(cf[8], cf[9]);
        bhi.u[1] = pkrtz(cf[10], cf[11]);
        bhi.u[2] = pkrtz(cf[12], cf[13]);
        bhi.u[3] = pkrtz(cf[14], cf[15]);

        // ---- view layer: accumulate feat into views partial, relu ----
        cv = MFMA32(awvlo, blo.v, cv);
        cv = MFMA32(awvhi, bhi.v, cv);

        blo.u[0] = relu2(pkrtz(cv[0], cv[1]));
        blo.u[1] = relu2(pkrtz(cv[2], cv[3]));
        blo.u[2] = relu2(pkrtz(cv[4], cv[5]));
        blo.u[3] = relu2(pkrtz(cv[6], cv[7]));
        bhi.u[0] = relu2(pkrtz(cv[8], cv[9]));
        bhi.u[1] = relu2(pkrtz(cv[10], cv[11]));
        bhi.u[2] = relu2(pkrtz(cv[12], cv[13]));
        bhi.u[3] = relu2(pkrtz(cv[14], cv[15]));

        // ---- rgb: 32 -> 3 (rows 0..2 valid; +br at store) ----
        f32x16 cr = MFMA32(awrlo, blo.v, zf);
        cr = MFMA32(awrhi, bhi.v, cr);

        // ---- store: hi==0 lanes hold rgb rows 0..2 for their point ----
        if (hi == 0) {
            float4 o = make_float4(cr[0] + br0, cr[1] + br1,
                                   cr[2] + br2, sg + bs0);
            *reinterpret_cast<float4*>(out + (size_t)(tile * 32 + m) * 4) = o;
        }
    }
}

extern "C" void kernel_launch(void* const* d_in, const int* in_sizes, int n_in,
                              void* d_out, int out_size, void* d_ws, size_t ws_size,
                              hipStream_t stream) {
    const float* x  = (const float*)d_in[0];
    const float* w0 = (const float*)d_in[1];
    const float* b0 = (const float*)d_in[2];
    const float* w1 = (const float*)d_in[3];
    const float* b1 = (const float*)d_in[4];
    const float* wf = (const float*)d_in[5];
    const float* bf = (const float*)d_in[6];
    const float* ws = (const float*)d_in[7];
    const float* bs = (const float*)d_in[8];
    const float* wv = (const float*)d_in[9];
    const float* bv = (const float*)d_in[10];
    const float* wr = (const float*)d_in[11];
    const float* br = (const float*)d_in[12];
    float* out = (float*)d_out;

    dim3 block(256);
    dim3 grid(2048);
    kilonerf_m32<<<grid, block, 0, stream>>>(x, w0, b0, w1, b1, wf, bf,
                                             ws, bs, wv, bv, wr, br, out);
}